// Round 7
// baseline (1367.460 us; speedup 1.0000x reference)
//
#include <hip/hip_runtime.h>
#include <hip/hip_bf16.h>
#include <math.h>

typedef __bf16 bf16_t;
typedef __bf16 bf16x8 __attribute__((ext_vector_type(8)));
typedef __bf16 bf16x4v __attribute__((ext_vector_type(4)));
typedef float floatx4 __attribute__((ext_vector_type(4)));

#define BM 128
#define BN 128
#define BK 64
#define LDT 72   // padded LDS row stride for legacy (reg-staged) kernels

// async global->LDS, 16B per lane. LDS dest is wave-uniform base + lane*16.
__device__ __forceinline__ void gload_lds16(const void* g, void* l) {
    __builtin_amdgcn_global_load_lds(
        (__attribute__((address_space(1))) void*)g,
        (__attribute__((address_space(3))) void*)l,
        16, 0, 0);
}

// XCD-aware bijective block swizzle (T1). Requires gx*gy % 8 == 0.
// Gives each XCD a contiguous chunk of the tile space for L2 panel reuse.
__device__ __forceinline__ void xcd_swizzle(int gx, int gy, int& bx, int& by) {
    const int nwg = gx * gy;
    const int bid = (int)blockIdx.y * gx + (int)blockIdx.x;
    const int cpx = nwg >> 3;
    const int s   = (bid & 7) * cpx + (bid >> 3);
    bx = s % gx;
    by = s / gx;
}

// split 8 f32 -> hi/lo bf16x8 (x ~= hi + lo, rel err ~2^-17)
__device__ __forceinline__ void split8(const float* p, bf16x8& hi, bf16x8& lo) {
    const float4* q = (const float4*)p;
    float4 a = q[0], b = q[1];
    float v[8] = { a.x, a.y, a.z, a.w, b.x, b.y, b.z, b.w };
#pragma unroll
    for (int i = 0; i < 8; ++i) {
        bf16_t h = (bf16_t)v[i];
        hi[i] = h;
        lo[i] = (bf16_t)(v[i] - (float)h);
    }
}

// ---- split-precision NT GEMM: C = A (MxK f32) * B^T (NxK f32) + bias ----
// 3-term compensated bf16 MFMA: hi*hi + hi*lo + lo*hi (~f32-grade).
template<bool OUT_SPLIT, bool HAS_BIAS>
__global__ __launch_bounds__(256, 2)
void gemm_nt_split(const float* __restrict__ A, const float* __restrict__ B,
                   const float* __restrict__ bias,
                   void* __restrict__ C0, bf16_t* __restrict__ Clo,
                   int M, int N, int K, int gx, int gy)
{
    __shared__ bf16_t Ah[BM * LDT];
    __shared__ bf16_t Al[BM * LDT];
    __shared__ bf16_t Bh[BN * LDT];
    __shared__ bf16_t Bl[BN * LDT];

    int bx, by;
    xcd_swizzle(gx, gy, bx, by);

    const int t    = threadIdx.x;
    const int m0   = bx * BM;
    const int n0   = by * BN;
    const int lane = t & 63;
    const int wm   = ((t >> 6) & 1) * 64;
    const int wn   = (t >> 7) * 64;
    const int lr   = lane & 15;
    const int lg   = lane >> 4;

    floatx4 acc[4][4] = {};

    for (int k0 = 0; k0 < K; k0 += BK) {
#pragma unroll
        for (int i = 0; i < 4; ++i) {
            int idx = t + i * 256;
            int row = idx >> 3;
            int col = (idx & 7) << 3;
            bf16x8 h, l;
            split8(&A[(size_t)(m0 + row) * K + k0 + col], h, l);
            *(bf16x8*)&Ah[row * LDT + col] = h;
            *(bf16x8*)&Al[row * LDT + col] = l;
            split8(&B[(size_t)(n0 + row) * K + k0 + col], h, l);
            *(bf16x8*)&Bh[row * LDT + col] = h;
            *(bf16x8*)&Bl[row * LDT + col] = l;
        }
        __syncthreads();
#pragma unroll
        for (int ks = 0; ks < BK; ks += 32) {
            bf16x8 ah[4], al[4], bh[4], bl[4];
#pragma unroll
            for (int mi = 0; mi < 4; ++mi) {
                ah[mi] = *(const bf16x8*)&Ah[(wm + mi * 16 + lr) * LDT + ks + lg * 8];
                al[mi] = *(const bf16x8*)&Al[(wm + mi * 16 + lr) * LDT + ks + lg * 8];
            }
#pragma unroll
            for (int ni = 0; ni < 4; ++ni) {
                bh[ni] = *(const bf16x8*)&Bh[(wn + ni * 16 + lr) * LDT + ks + lg * 8];
                bl[ni] = *(const bf16x8*)&Bl[(wn + ni * 16 + lr) * LDT + ks + lg * 8];
            }
#pragma unroll
            for (int mi = 0; mi < 4; ++mi)
#pragma unroll
                for (int ni = 0; ni < 4; ++ni) {
                    acc[mi][ni] = __builtin_amdgcn_mfma_f32_16x16x32_bf16(ah[mi], bh[ni], acc[mi][ni], 0, 0, 0);
                    acc[mi][ni] = __builtin_amdgcn_mfma_f32_16x16x32_bf16(ah[mi], bl[ni], acc[mi][ni], 0, 0, 0);
                    acc[mi][ni] = __builtin_amdgcn_mfma_f32_16x16x32_bf16(al[mi], bh[ni], acc[mi][ni], 0, 0, 0);
                }
        }
        __syncthreads();
    }

#pragma unroll
    for (int mi = 0; mi < 4; ++mi)
#pragma unroll
        for (int ni = 0; ni < 4; ++ni) {
            int col = n0 + wn + ni * 16 + lr;
            float bv = 0.0f;
            if constexpr (HAS_BIAS) bv = bias[col];
#pragma unroll
            for (int r = 0; r < 4; ++r) {
                int row = m0 + wm + mi * 16 + lg * 4 + r;
                float v = acc[mi][ni][r] + bv;
                if constexpr (OUT_SPLIT) {
                    bf16_t h = (bf16_t)v;
                    ((bf16_t*)C0)[(size_t)row * N + col] = h;
                    Clo[(size_t)row * N + col] = (bf16_t)(v - (float)h);
                } else {
                    ((float*)C0)[(size_t)row * N + col] = v;
                }
            }
        }
}

// ---- pre-split NT GEMM via global_load_lds + XOR swizzle ----
// C(f32) = (Ahi+Alo)*(Bhi+Blo)^T; epilogue also emits per-column softmax
// partials (max, sumexp) over this block's 128 rows -> pm/pz[64][8192].
__global__ __launch_bounds__(256, 2)
void gemm_nt_pre_async(const bf16_t* __restrict__ Ahi, const bf16_t* __restrict__ Alo,
                       const bf16_t* __restrict__ Bhi, const bf16_t* __restrict__ Blo,
                       float* __restrict__ C, float* __restrict__ pm,
                       float* __restrict__ pz, int M, int N, int K, int gx, int gy)
{
    __shared__ bf16_t Ah[BM * BK];
    __shared__ bf16_t Al[BM * BK];
    __shared__ bf16_t Bh[BN * BK];
    __shared__ bf16_t Bl[BN * BK];
    __shared__ float red_m[2][128];
    __shared__ float red_z[2][128];

    int bx, by;
    xcd_swizzle(gx, gy, bx, by);

    const int t    = threadIdx.x;
    const int m0   = bx * BM;
    const int n0   = by * BN;
    const int lane = t & 63;
    const int wv   = t >> 6;
    const int widm = (t >> 6) & 1;
    const int wm   = widm * 64;
    const int wn   = (t >> 7) * 64;
    const int lr   = lane & 15;
    const int lg   = lane >> 4;
    const int lrow = lane >> 3;
    const int lcol = (((lane & 7) ^ lrow) * 8);
    const int swz  = (lr & 7) << 3;

    floatx4 acc[4][4] = {};

    for (int k0 = 0; k0 < K; k0 += BK) {
#pragma unroll
        for (int i = 0; i < 4; ++i) {
            const int seg = wv * 4 + i;
            const int row = seg * 8 + lrow;
            const size_t ga = (size_t)(m0 + row) * K + k0 + lcol;
            const size_t gb = (size_t)(n0 + row) * K + k0 + lcol;
            gload_lds16(&Ahi[ga], &Ah[seg * 512]);
            gload_lds16(&Alo[ga], &Al[seg * 512]);
            gload_lds16(&Bhi[gb], &Bh[seg * 512]);
            gload_lds16(&Blo[gb], &Bl[seg * 512]);
        }
        __syncthreads();
#pragma unroll
        for (int ks = 0; ks < BK; ks += 32) {
            const int cA = (ks + lg * 8) ^ swz;
            bf16x8 ah[4], al[4], bh[4], bl[4];
#pragma unroll
            for (int mi = 0; mi < 4; ++mi) {
                ah[mi] = *(const bf16x8*)&Ah[(wm + mi * 16 + lr) * BK + cA];
                al[mi] = *(const bf16x8*)&Al[(wm + mi * 16 + lr) * BK + cA];
            }
#pragma unroll
            for (int ni = 0; ni < 4; ++ni) {
                bh[ni] = *(const bf16x8*)&Bh[(wn + ni * 16 + lr) * BK + cA];
                bl[ni] = *(const bf16x8*)&Bl[(wn + ni * 16 + lr) * BK + cA];
            }
#pragma unroll
            for (int mi = 0; mi < 4; ++mi)
#pragma unroll
                for (int ni = 0; ni < 4; ++ni) {
                    acc[mi][ni] = __builtin_amdgcn_mfma_f32_16x16x32_bf16(ah[mi], bh[ni], acc[mi][ni], 0, 0, 0);
                    acc[mi][ni] = __builtin_amdgcn_mfma_f32_16x16x32_bf16(ah[mi], bl[ni], acc[mi][ni], 0, 0, 0);
                    acc[mi][ni] = __builtin_amdgcn_mfma_f32_16x16x32_bf16(al[mi], bh[ni], acc[mi][ni], 0, 0, 0);
                }
        }
        __syncthreads();
    }

    // ---- C write ----
#pragma unroll
    for (int mi = 0; mi < 4; ++mi)
#pragma unroll
        for (int ni = 0; ni < 4; ++ni) {
            int col = n0 + wn + ni * 16 + lr;
#pragma unroll
            for (int r = 0; r < 4; ++r) {
                int row = m0 + wm + mi * 16 + lg * 4 + r;
                C[(size_t)row * N + col] = acc[mi][ni][r];
            }
        }

    // ---- per-column softmax partial over this block's 128 rows ----
#pragma unroll
    for (int ni = 0; ni < 4; ++ni) {
        float lm = -INFINITY;
#pragma unroll
        for (int mi = 0; mi < 4; ++mi)
#pragma unroll
            for (int r = 0; r < 4; ++r) lm = fmaxf(lm, acc[mi][ni][r]);
        float lz = 0.0f;
#pragma unroll
        for (int mi = 0; mi < 4; ++mi)
#pragma unroll
            for (int r = 0; r < 4; ++r) lz += __expf(acc[mi][ni][r] - lm);
#pragma unroll
        for (int off = 16; off <= 32; off <<= 1) {
            float om = __shfl_xor(lm, off);
            float oz = __shfl_xor(lz, off);
            float nm = fmaxf(lm, om);
            lz = lz * __expf(lm - nm) + oz * __expf(om - nm);
            lm = nm;
        }
        if (lg == 0) {
            red_m[widm][wn + ni * 16 + lr] = lm;
            red_z[widm][wn + ni * 16 + lr] = lz;
        }
    }
    __syncthreads();
    if (t < 128) {
        float a = red_m[0][t], b = red_m[1][t];
        float za = red_z[0][t], zb = red_z[1][t];
        float mb = fmaxf(a, b);
        float z  = za * __expf(a - mb) + zb * __expf(b - mb);
        pm[(size_t)bx * 8192 + n0 + t] = mb;
        pz[(size_t)bx * 8192 + n0 + t] = z;
    }
}

// ---- plain bf16 NT GEMM via global_load_lds + XOR swizzle: C(f32) = A * B^T ----
__global__ __launch_bounds__(256, 2)
void gemm_nt_bf16_async(const bf16_t* __restrict__ A, const bf16_t* __restrict__ B,
                        float* __restrict__ C, int M, int N, int K, int gx, int gy)
{
    __shared__ bf16_t As[BM * BK];
    __shared__ bf16_t Bs[BN * BK];

    int bx, by;
    xcd_swizzle(gx, gy, bx, by);

    const int t    = threadIdx.x;
    const int m0   = bx * BM;
    const int n0   = by * BN;
    const int lane = t & 63;
    const int wv   = t >> 6;
    const int wm   = ((t >> 6) & 1) * 64;
    const int wn   = (t >> 7) * 64;
    const int lr   = lane & 15;
    const int lg   = lane >> 4;
    const int lrow = lane >> 3;
    const int lcol = (((lane & 7) ^ lrow) * 8);
    const int swz  = (lr & 7) << 3;

    floatx4 acc[4][4] = {};

    for (int k0 = 0; k0 < K; k0 += BK) {
#pragma unroll
        for (int i = 0; i < 4; ++i) {
            const int seg = wv * 4 + i;
            const int row = seg * 8 + lrow;
            gload_lds16(&A[(size_t)(m0 + row) * K + k0 + lcol], &As[seg * 512]);
            gload_lds16(&B[(size_t)(n0 + row) * K + k0 + lcol], &Bs[seg * 512]);
        }
        __syncthreads();
#pragma unroll
        for (int ks = 0; ks < BK; ks += 32) {
            const int cA = (ks + lg * 8) ^ swz;
            bf16x8 a[4], b[4];
#pragma unroll
            for (int mi = 0; mi < 4; ++mi)
                a[mi] = *(const bf16x8*)&As[(wm + mi * 16 + lr) * BK + cA];
#pragma unroll
            for (int ni = 0; ni < 4; ++ni)
                b[ni] = *(const bf16x8*)&Bs[(wn + ni * 16 + lr) * BK + cA];
#pragma unroll
            for (int mi = 0; mi < 4; ++mi)
#pragma unroll
                for (int ni = 0; ni < 4; ++ni)
                    acc[mi][ni] = __builtin_amdgcn_mfma_f32_16x16x32_bf16(
                        a[mi], b[ni], acc[mi][ni], 0, 0, 0);
        }
        __syncthreads();
    }

#pragma unroll
    for (int mi = 0; mi < 4; ++mi)
#pragma unroll
        for (int ni = 0; ni < 4; ++ni) {
            int col = n0 + wn + ni * 16 + lr;
#pragma unroll
            for (int r = 0; r < 4; ++r) {
                int row = m0 + wm + mi * 16 + lg * 4 + r;
                C[(size_t)row * N + col] = acc[mi][ni][r];
            }
        }
}

// ---- 64x64-tile transpose + f32->bf16: src [R,C] f32 -> dst [C,R] bf16 ----
__global__ __launch_bounds__(256)
void transpose_to_bf16(const float* __restrict__ src, bf16_t* __restrict__ dst,
                       int R, int Ccols)
{
    __shared__ float tile[64][65];
    const int r0 = blockIdx.x * 64;
    const int c0 = blockIdx.y * 64;
    const int tr = threadIdx.x >> 4;
    const int tc = (threadIdx.x & 15) * 4;
#pragma unroll
    for (int i = 0; i < 4; ++i) {
        int r = tr + i * 16;
        float4 v = *(const float4*)&src[(size_t)(r0 + r) * Ccols + c0 + tc];
        tile[r][tc + 0] = v.x; tile[r][tc + 1] = v.y;
        tile[r][tc + 2] = v.z; tile[r][tc + 3] = v.w;
    }
    __syncthreads();
#pragma unroll
    for (int i = 0; i < 4; ++i) {
        int c = tr + i * 16;
        bf16x4v o = { (bf16_t)tile[tc + 0][c], (bf16_t)tile[tc + 1][c],
                      (bf16_t)tile[tc + 2][c], (bf16_t)tile[tc + 3][c] };
        *(bf16x4v*)&dst[(size_t)(c0 + c) * R + r0 + tc] = o;
    }
}

// ---- column softmax combine over 64 per-block partials ----
__global__ __launch_bounds__(256)
void col_softmax_combine64(const float* __restrict__ pm, const float* __restrict__ pz,
                           float* __restrict__ mf, float* __restrict__ iz)
{
    int j = blockIdx.x * 256 + threadIdx.x;
    float m = -INFINITY;
#pragma unroll
    for (int c = 0; c < 64; ++c) m = fmaxf(m, pm[(size_t)c * 8192 + j]);
    float z = 0.0f;
#pragma unroll
    for (int c = 0; c < 64; ++c) z += pz[(size_t)c * 8192 + j] * __expf(pm[(size_t)c * 8192 + j] - m);
    mf[j] = m;
    iz[j] = 1.0f / z;
}

// normalize + also emit bf16 copy of attns for the fused GEMM
__global__ __launch_bounds__(256)
void normalize_attn_bf16(float* __restrict__ sc, const float* __restrict__ mf,
                         const float* __restrict__ iz, bf16_t* __restrict__ ab)
{
    size_t base = ((size_t)blockIdx.x * 256 + threadIdx.x) * 4;
    int j = (int)(base & 8191);
    float4 s  = *(float4*)&sc[base];
    float4 m4 = *(const float4*)&mf[j];
    float4 z4 = *(const float4*)&iz[j];
    s.x = __expf(s.x - m4.x) * z4.x;
    s.y = __expf(s.y - m4.y) * z4.y;
    s.z = __expf(s.z - m4.z) * z4.z;
    s.w = __expf(s.w - m4.w) * z4.w;
    *(float4*)&sc[base] = s;
    bf16x4v b = { (bf16_t)s.x, (bf16_t)s.y, (bf16_t)s.z, (bf16_t)s.w };
    *(bf16x4v*)&ab[base] = b;
}

extern "C" void kernel_launch(void* const* d_in, const int* in_sizes, int n_in,
                              void* d_out, int out_size, void* d_ws, size_t ws_size,
                              hipStream_t stream) {
    const float* sent  = (const float*)d_in[0];   // [8192,1024]
    const float* knowl = (const float*)d_in[1];   // [8192,2048]
    const float* Ws    = (const float*)d_in[2];   // [1024,1024]
    const float* bs    = (const float*)d_in[3];   // [1024]
    const float* Wk    = (const float*)d_in[4];   // [1024,2048]
    const float* bk    = (const float*)d_in[5];   // [1024]

    float* attns = (float*)d_out;                               // [8192,8192]
    float* fused = (float*)d_out + (size_t)8192 * 8192;         // [8192,2048]

    const size_t MB = 1024 * 1024;
    char* ws = (char*)d_ws;
    dim3 blk(256);

    // layout: Shi(16)@0 Slo(16)@16 Khi(16)@32 Klo(16)@48 [dead after scores]
    //         Ab(128)@0 overlays them; Vt(32)@128; pm/pz@160/162; mf/iz@164
    bf16_t* Shi = (bf16_t*)(ws + 0 * MB);
    bf16_t* Slo = (bf16_t*)(ws + 16 * MB);
    bf16_t* Khi = (bf16_t*)(ws + 32 * MB);
    bf16_t* Klo = (bf16_t*)(ws + 48 * MB);
    bf16_t* Ab  = (bf16_t*)(ws);
    bf16_t* Vt  = (bf16_t*)(ws + 128 * MB);
    float*  pm  = (float*)(ws + 160 * MB);
    float*  pz  = (float*)(ws + 162 * MB);
    float*  mf  = (float*)(ws + 164 * MB);
    float*  iz  = mf + 8192;

    // 1) projections: S = sent @ Ws^T + bs, K = knowl @ Wk^T + bk (split out)
    gemm_nt_split<true, true><<<dim3(64, 8), blk, 0, stream>>>(
        sent, Ws, bs, Shi, Slo, 8192, 1024, 1024, 64, 8);
    gemm_nt_split<true, true><<<dim3(64, 8), blk, 0, stream>>>(
        knowl, Wk, bk, Khi, Klo, 8192, 1024, 2048, 64, 8);
    // 2) scores = S @ K^T (compensated) + per-block softmax partials
    gemm_nt_pre_async<<<dim3(64, 64), blk, 0, stream>>>(
        Shi, Slo, Khi, Klo, attns, pm, pz, 8192, 8192, 1024, 64, 64);
    // 3) Vt = knowl^T bf16 (overlays dead Khi/Klo)
    transpose_to_bf16<<<dim3(128, 32), blk, 0, stream>>>(knowl, Vt, 8192, 2048);
    // 4) softmax combine + normalize (also emits bf16 attns copy into Ab)
    col_softmax_combine64<<<dim3(32), blk, 0, stream>>>(pm, pz, mf, iz);
    normalize_attn_bf16<<<dim3(65536), blk, 0, stream>>>(attns, mf, iz, Ab);
    // 5) fused = attns @ V == Ab @ Vt^T
    gemm_nt_bf16_async<<<dim3(64, 16), blk, 0, stream>>>(
        Ab, Vt, fused, 8192, 2048, 8192, 64, 16);
}

// Round 8
// 1352.405 us; speedup vs baseline: 1.0111x; 1.0111x over previous
//
#include <hip/hip_runtime.h>
#include <hip/hip_bf16.h>
#include <math.h>

typedef __bf16 bf16_t;
typedef __bf16 bf16x8 __attribute__((ext_vector_type(8)));
typedef __bf16 bf16x4v __attribute__((ext_vector_type(4)));
typedef float floatx4 __attribute__((ext_vector_type(4)));

#define BM 128
#define BN 128
#define BK 64
#define LDT 72   // padded LDS row stride for reg-staged projection segment

// async global->LDS, 16B per lane. LDS dest is wave-uniform base + lane*16.
__device__ __forceinline__ void gload_lds16(const void* g, void* l) {
    __builtin_amdgcn_global_load_lds(
        (__attribute__((address_space(1))) void*)g,
        (__attribute__((address_space(3))) void*)l,
        16, 0, 0);
}

// split 8 f32 -> hi/lo bf16x8 (x ~= hi + lo, rel err ~2^-17)
__device__ __forceinline__ void split8(const float* p, bf16x8& hi, bf16x8& lo) {
    const float4* q = (const float4*)p;
    float4 a = q[0], b = q[1];
    float v[8] = { a.x, a.y, a.z, a.w, b.x, b.y, b.z, b.w };
#pragma unroll
    for (int i = 0; i < 8; ++i) {
        bf16_t h = (bf16_t)v[i];
        hi[i] = h;
        lo[i] = (bf16_t)(v[i] - (float)h);
    }
}

// ---- projection segment: C = A (MxK f32) * B^T (NxK f32) + bias,
// split-output (hi/lo bf16). Verified gemm_nt_split body, LDS via smem. ----
__device__ void proj_segment(char* smem,
                             const float* __restrict__ A, const float* __restrict__ B,
                             const float* __restrict__ bias,
                             bf16_t* __restrict__ Chi, bf16_t* __restrict__ Clo,
                             int M, int N, int K, int bx, int by)
{
    bf16_t* Ah = (bf16_t*)smem;
    bf16_t* Al = Ah + BM * LDT;
    bf16_t* Bh = Al + BM * LDT;
    bf16_t* Bl = Bh + BN * LDT;

    const int t    = threadIdx.x;
    const int m0   = bx * BM;
    const int n0   = by * BN;
    const int lane = t & 63;
    const int wm   = ((t >> 6) & 1) * 64;
    const int wn   = (t >> 7) * 64;
    const int lr   = lane & 15;
    const int lg   = lane >> 4;

    floatx4 acc[4][4] = {};

    for (int k0 = 0; k0 < K; k0 += BK) {
#pragma unroll
        for (int i = 0; i < 4; ++i) {
            int idx = t + i * 256;
            int row = idx >> 3;
            int col = (idx & 7) << 3;
            bf16x8 h, l;
            split8(&A[(size_t)(m0 + row) * K + k0 + col], h, l);
            *(bf16x8*)&Ah[row * LDT + col] = h;
            *(bf16x8*)&Al[row * LDT + col] = l;
            split8(&B[(size_t)(n0 + row) * K + k0 + col], h, l);
            *(bf16x8*)&Bh[row * LDT + col] = h;
            *(bf16x8*)&Bl[row * LDT + col] = l;
        }
        __syncthreads();
#pragma unroll
        for (int ks = 0; ks < BK; ks += 32) {
            bf16x8 ah[4], al[4], bh[4], bl[4];
#pragma unroll
            for (int mi = 0; mi < 4; ++mi) {
                ah[mi] = *(const bf16x8*)&Ah[(wm + mi * 16 + lr) * LDT + ks + lg * 8];
                al[mi] = *(const bf16x8*)&Al[(wm + mi * 16 + lr) * LDT + ks + lg * 8];
            }
#pragma unroll
            for (int ni = 0; ni < 4; ++ni) {
                bh[ni] = *(const bf16x8*)&Bh[(wn + ni * 16 + lr) * LDT + ks + lg * 8];
                bl[ni] = *(const bf16x8*)&Bl[(wn + ni * 16 + lr) * LDT + ks + lg * 8];
            }
#pragma unroll
            for (int mi = 0; mi < 4; ++mi)
#pragma unroll
                for (int ni = 0; ni < 4; ++ni) {
                    acc[mi][ni] = __builtin_amdgcn_mfma_f32_16x16x32_bf16(ah[mi], bh[ni], acc[mi][ni], 0, 0, 0);
                    acc[mi][ni] = __builtin_amdgcn_mfma_f32_16x16x32_bf16(ah[mi], bl[ni], acc[mi][ni], 0, 0, 0);
                    acc[mi][ni] = __builtin_amdgcn_mfma_f32_16x16x32_bf16(al[mi], bh[ni], acc[mi][ni], 0, 0, 0);
                }
        }
        __syncthreads();
    }

#pragma unroll
    for (int mi = 0; mi < 4; ++mi)
#pragma unroll
        for (int ni = 0; ni < 4; ++ni) {
            int col = n0 + wn + ni * 16 + lr;
            float bv = bias[col];
#pragma unroll
            for (int r = 0; r < 4; ++r) {
                int row = m0 + wm + mi * 16 + lg * 4 + r;
                float v = acc[mi][ni][r] + bv;
                bf16_t h = (bf16_t)v;
                Chi[(size_t)row * N + col] = h;
                Clo[(size_t)row * N + col] = (bf16_t)(v - (float)h);
            }
        }
}

// ---- transpose segment: 64x64 tile, f32 [R,C] -> bf16 [C,R] ----
__device__ void transpose_segment(char* smem,
                                  const float* __restrict__ src, bf16_t* __restrict__ dst,
                                  int R, int Ccols, int tbx, int tby)
{
    float (*tile)[65] = (float (*)[65])smem;   // 64*65*4 = 16640 B
    const int r0 = tbx * 64;
    const int c0 = tby * 64;
    const int tr = threadIdx.x >> 4;
    const int tc = (threadIdx.x & 15) * 4;
#pragma unroll
    for (int i = 0; i < 4; ++i) {
        int r = tr + i * 16;
        float4 v = *(const float4*)&src[(size_t)(r0 + r) * Ccols + c0 + tc];
        tile[r][tc + 0] = v.x; tile[r][tc + 1] = v.y;
        tile[r][tc + 2] = v.z; tile[r][tc + 3] = v.w;
    }
    __syncthreads();
#pragma unroll
    for (int i = 0; i < 4; ++i) {
        int c = tr + i * 16;
        bf16x4v o = { (bf16_t)tile[tc + 0][c], (bf16_t)tile[tc + 1][c],
                      (bf16_t)tile[tc + 2][c], (bf16_t)tile[tc + 3][c] };
        *(bf16x4v*)&dst[(size_t)(c0 + c) * R + r0 + tc] = o;
    }
}

// ---- merged prep: proj1 (512 blk) + proj2 (512 blk) + V-transpose (4096 blk) ----
// Segments are block-uniform; LDS buffer shared by cast. Overlaps the three
// stages' ramps/tails that were previously serialized by stream order.
__global__ __launch_bounds__(256, 2)
void prep_fused(const float* __restrict__ sent, const float* __restrict__ Ws,
                const float* __restrict__ bs,
                const float* __restrict__ knowl, const float* __restrict__ Wk,
                const float* __restrict__ bk,
                bf16_t* __restrict__ Shi, bf16_t* __restrict__ Slo,
                bf16_t* __restrict__ Khi, bf16_t* __restrict__ Klo,
                bf16_t* __restrict__ Vt)
{
    __shared__ char smem[4 * BM * LDT * sizeof(bf16_t)];   // 73728 B
    const int bid = blockIdx.x;
    if (bid < 512) {
        proj_segment(smem, sent, Ws, bs, Shi, Slo, 8192, 1024, 1024,
                     bid & 63, bid >> 6);
    } else if (bid < 1024) {
        const int b = bid - 512;
        proj_segment(smem, knowl, Wk, bk, Khi, Klo, 8192, 1024, 2048,
                     b & 63, b >> 6);
    } else {
        const int b = bid - 1024;
        transpose_segment(smem, knowl, Vt, 8192, 2048, b & 127, b >> 7);
    }
}

// ---- pre-split NT GEMM via global_load_lds + XOR swizzle ----
// C(f32) = (Ahi+Alo)*(Bhi+Blo)^T; epilogue also emits per-column softmax
// partials (max, sumexp) over this block's 128 rows -> pm/pz[64][8192].
__global__ __launch_bounds__(256, 2)
void gemm_nt_pre_async(const bf16_t* __restrict__ Ahi, const bf16_t* __restrict__ Alo,
                       const bf16_t* __restrict__ Bhi, const bf16_t* __restrict__ Blo,
                       float* __restrict__ C, float* __restrict__ pm,
                       float* __restrict__ pz, int M, int N, int K)
{
    __shared__ bf16_t Ah[BM * BK];
    __shared__ bf16_t Al[BM * BK];
    __shared__ bf16_t Bh[BN * BK];
    __shared__ bf16_t Bl[BN * BK];
    __shared__ float red_m[2][128];
    __shared__ float red_z[2][128];

    const int t    = threadIdx.x;
    const int m0   = blockIdx.x * BM;
    const int n0   = blockIdx.y * BN;
    const int lane = t & 63;
    const int wv   = t >> 6;
    const int widm = (t >> 6) & 1;
    const int wm   = widm * 64;
    const int wn   = (t >> 7) * 64;
    const int lr   = lane & 15;
    const int lg   = lane >> 4;
    const int lrow = lane >> 3;
    const int lcol = (((lane & 7) ^ lrow) * 8);
    const int swz  = (lr & 7) << 3;

    floatx4 acc[4][4] = {};

    for (int k0 = 0; k0 < K; k0 += BK) {
#pragma unroll
        for (int i = 0; i < 4; ++i) {
            const int seg = wv * 4 + i;
            const int row = seg * 8 + lrow;
            const size_t ga = (size_t)(m0 + row) * K + k0 + lcol;
            const size_t gb = (size_t)(n0 + row) * K + k0 + lcol;
            gload_lds16(&Ahi[ga], &Ah[seg * 512]);
            gload_lds16(&Alo[ga], &Al[seg * 512]);
            gload_lds16(&Bhi[gb], &Bh[seg * 512]);
            gload_lds16(&Blo[gb], &Bl[seg * 512]);
        }
        __syncthreads();
#pragma unroll
        for (int ks = 0; ks < BK; ks += 32) {
            const int cA = (ks + lg * 8) ^ swz;
            bf16x8 ah[4], al[4], bh[4], bl[4];
#pragma unroll
            for (int mi = 0; mi < 4; ++mi) {
                ah[mi] = *(const bf16x8*)&Ah[(wm + mi * 16 + lr) * BK + cA];
                al[mi] = *(const bf16x8*)&Al[(wm + mi * 16 + lr) * BK + cA];
            }
#pragma unroll
            for (int ni = 0; ni < 4; ++ni) {
                bh[ni] = *(const bf16x8*)&Bh[(wn + ni * 16 + lr) * BK + cA];
                bl[ni] = *(const bf16x8*)&Bl[(wn + ni * 16 + lr) * BK + cA];
            }
#pragma unroll
            for (int mi = 0; mi < 4; ++mi)
#pragma unroll
                for (int ni = 0; ni < 4; ++ni) {
                    acc[mi][ni] = __builtin_amdgcn_mfma_f32_16x16x32_bf16(ah[mi], bh[ni], acc[mi][ni], 0, 0, 0);
                    acc[mi][ni] = __builtin_amdgcn_mfma_f32_16x16x32_bf16(ah[mi], bl[ni], acc[mi][ni], 0, 0, 0);
                    acc[mi][ni] = __builtin_amdgcn_mfma_f32_16x16x32_bf16(al[mi], bh[ni], acc[mi][ni], 0, 0, 0);
                }
        }
        __syncthreads();
    }

    // ---- C write ----
#pragma unroll
    for (int mi = 0; mi < 4; ++mi)
#pragma unroll
        for (int ni = 0; ni < 4; ++ni) {
            int col = n0 + wn + ni * 16 + lr;
#pragma unroll
            for (int r = 0; r < 4; ++r) {
                int row = m0 + wm + mi * 16 + lg * 4 + r;
                C[(size_t)row * N + col] = acc[mi][ni][r];
            }
        }

    // ---- per-column softmax partial over this block's 128 rows ----
#pragma unroll
    for (int ni = 0; ni < 4; ++ni) {
        float lm = -INFINITY;
#pragma unroll
        for (int mi = 0; mi < 4; ++mi)
#pragma unroll
            for (int r = 0; r < 4; ++r) lm = fmaxf(lm, acc[mi][ni][r]);
        float lz = 0.0f;
#pragma unroll
        for (int mi = 0; mi < 4; ++mi)
#pragma unroll
            for (int r = 0; r < 4; ++r) lz += __expf(acc[mi][ni][r] - lm);
#pragma unroll
        for (int off = 16; off <= 32; off <<= 1) {
            float om = __shfl_xor(lm, off);
            float oz = __shfl_xor(lz, off);
            float nm = fmaxf(lm, om);
            lz = lz * __expf(lm - nm) + oz * __expf(om - nm);
            lm = nm;
        }
        if (lg == 0) {
            red_m[widm][wn + ni * 16 + lr] = lm;
            red_z[widm][wn + ni * 16 + lr] = lz;
        }
    }
    __syncthreads();
    if (t < 128) {
        float a = red_m[0][t], b = red_m[1][t];
        float za = red_z[0][t], zb = red_z[1][t];
        float mb = fmaxf(a, b);
        float z  = za * __expf(a - mb) + zb * __expf(b - mb);
        pm[(size_t)blockIdx.x * 8192 + n0 + t] = mb;
        pz[(size_t)blockIdx.x * 8192 + n0 + t] = z;
    }
}

// ---- plain bf16 NT GEMM via global_load_lds + XOR swizzle: C(f32) = A * B^T ----
__global__ __launch_bounds__(256, 2)
void gemm_nt_bf16_async(const bf16_t* __restrict__ A, const bf16_t* __restrict__ B,
                        float* __restrict__ C, int M, int N, int K)
{
    __shared__ bf16_t As[BM * BK];
    __shared__ bf16_t Bs[BN * BK];

    const int t    = threadIdx.x;
    const int m0   = blockIdx.x * BM;
    const int n0   = blockIdx.y * BN;
    const int lane = t & 63;
    const int wv   = t >> 6;
    const int wm   = ((t >> 6) & 1) * 64;
    const int wn   = (t >> 7) * 64;
    const int lr   = lane & 15;
    const int lg   = lane >> 4;
    const int lrow = lane >> 3;
    const int lcol = (((lane & 7) ^ lrow) * 8);
    const int swz  = (lr & 7) << 3;

    floatx4 acc[4][4] = {};

    for (int k0 = 0; k0 < K; k0 += BK) {
#pragma unroll
        for (int i = 0; i < 4; ++i) {
            const int seg = wv * 4 + i;
            const int row = seg * 8 + lrow;
            gload_lds16(&A[(size_t)(m0 + row) * K + k0 + lcol], &As[seg * 512]);
            gload_lds16(&B[(size_t)(n0 + row) * K + k0 + lcol], &Bs[seg * 512]);
        }
        __syncthreads();
#pragma unroll
        for (int ks = 0; ks < BK; ks += 32) {
            const int cA = (ks + lg * 8) ^ swz;
            bf16x8 a[4], b[4];
#pragma unroll
            for (int mi = 0; mi < 4; ++mi)
                a[mi] = *(const bf16x8*)&As[(wm + mi * 16 + lr) * BK + cA];
#pragma unroll
            for (int ni = 0; ni < 4; ++ni)
                b[ni] = *(const bf16x8*)&Bs[(wn + ni * 16 + lr) * BK + cA];
#pragma unroll
            for (int mi = 0; mi < 4; ++mi)
#pragma unroll
                for (int ni = 0; ni < 4; ++ni)
                    acc[mi][ni] = __builtin_amdgcn_mfma_f32_16x16x32_bf16(
                        a[mi], b[ni], acc[mi][ni], 0, 0, 0);
        }
        __syncthreads();
    }

#pragma unroll
    for (int mi = 0; mi < 4; ++mi)
#pragma unroll
        for (int ni = 0; ni < 4; ++ni) {
            int col = n0 + wn + ni * 16 + lr;
#pragma unroll
            for (int r = 0; r < 4; ++r) {
                int row = m0 + wm + mi * 16 + lg * 4 + r;
                C[(size_t)row * N + col] = acc[mi][ni][r];
            }
        }
}

// ---- column softmax combine over 64 per-block partials ----
__global__ __launch_bounds__(256)
void col_softmax_combine64(const float* __restrict__ pm, const float* __restrict__ pz,
                           float* __restrict__ mf, float* __restrict__ iz)
{
    int j = blockIdx.x * 256 + threadIdx.x;
    float m = -INFINITY;
#pragma unroll
    for (int c = 0; c < 64; ++c) m = fmaxf(m, pm[(size_t)c * 8192 + j]);
    float z = 0.0f;
#pragma unroll
    for (int c = 0; c < 64; ++c) z += pz[(size_t)c * 8192 + j] * __expf(pm[(size_t)c * 8192 + j] - m);
    mf[j] = m;
    iz[j] = 1.0f / z;
}

// normalize + also emit bf16 copy of attns for the fused GEMM
__global__ __launch_bounds__(256)
void normalize_attn_bf16(float* __restrict__ sc, const float* __restrict__ mf,
                         const float* __restrict__ iz, bf16_t* __restrict__ ab)
{
    size_t base = ((size_t)blockIdx.x * 256 + threadIdx.x) * 4;
    int j = (int)(base & 8191);
    float4 s  = *(float4*)&sc[base];
    float4 m4 = *(const float4*)&mf[j];
    float4 z4 = *(const float4*)&iz[j];
    s.x = __expf(s.x - m4.x) * z4.x;
    s.y = __expf(s.y - m4.y) * z4.y;
    s.z = __expf(s.z - m4.z) * z4.z;
    s.w = __expf(s.w - m4.w) * z4.w;
    *(float4*)&sc[base] = s;
    bf16x4v b = { (bf16_t)s.x, (bf16_t)s.y, (bf16_t)s.z, (bf16_t)s.w };
    *(bf16x4v*)&ab[base] = b;
}

extern "C" void kernel_launch(void* const* d_in, const int* in_sizes, int n_in,
                              void* d_out, int out_size, void* d_ws, size_t ws_size,
                              hipStream_t stream) {
    const float* sent  = (const float*)d_in[0];   // [8192,1024]
    const float* knowl = (const float*)d_in[1];   // [8192,2048]
    const float* Ws    = (const float*)d_in[2];   // [1024,1024]
    const float* bs    = (const float*)d_in[3];   // [1024]
    const float* Wk    = (const float*)d_in[4];   // [1024,2048]
    const float* bk    = (const float*)d_in[5];   // [1024]

    float* attns = (float*)d_out;                               // [8192,8192]
    float* fused = (float*)d_out + (size_t)8192 * 8192;         // [8192,2048]

    const size_t MB = 1024 * 1024;
    char* ws = (char*)d_ws;
    dim3 blk(256);

    // layout: Shi(16)@0 Slo(16)@16 Khi(16)@32 Klo(16)@48 [dead after scores]
    //         Ab(128)@0 overlays them; Vt(32)@128; pm/pz@160/162; mf/iz@164
    bf16_t* Shi = (bf16_t*)(ws + 0 * MB);
    bf16_t* Slo = (bf16_t*)(ws + 16 * MB);
    bf16_t* Khi = (bf16_t*)(ws + 32 * MB);
    bf16_t* Klo = (bf16_t*)(ws + 48 * MB);
    bf16_t* Ab  = (bf16_t*)(ws);
    bf16_t* Vt  = (bf16_t*)(ws + 128 * MB);
    float*  pm  = (float*)(ws + 160 * MB);
    float*  pz  = (float*)(ws + 162 * MB);
    float*  mf  = (float*)(ws + 164 * MB);
    float*  iz  = mf + 8192;

    // 1) merged prep: S/K projections (split out) + Vt = knowl^T bf16
    prep_fused<<<dim3(5120), blk, 0, stream>>>(
        sent, Ws, bs, knowl, Wk, bk, Shi, Slo, Khi, Klo, Vt);
    // 2) scores = S @ K^T (compensated) + per-block softmax partials
    gemm_nt_pre_async<<<dim3(64, 64), blk, 0, stream>>>(
        Shi, Slo, Khi, Klo, attns, pm, pz, 8192, 8192, 1024);
    // 3) softmax combine + normalize (also emits bf16 attns copy into Ab)
    col_softmax_combine64<<<dim3(32), blk, 0, stream>>>(pm, pz, mf, iz);
    normalize_attn_bf16<<<dim3(65536), blk, 0, stream>>>(attns, mf, iz, Ab);
    // 4) fused = attns @ V == Ab @ Vt^T
    gemm_nt_bf16_async<<<dim3(64, 16), blk, 0, stream>>>(
        Ab, Vt, fused, 8192, 2048, 8192);
}

// Round 9
// 1261.724 us; speedup vs baseline: 1.0838x; 1.0719x over previous
//
#include <hip/hip_runtime.h>
#include <hip/hip_bf16.h>
#include <math.h>

typedef __bf16 bf16_t;
typedef __bf16 bf16x8 __attribute__((ext_vector_type(8)));
typedef __bf16 bf16x4v __attribute__((ext_vector_type(4)));
typedef float floatx4 __attribute__((ext_vector_type(4)));

#define BM 128
#define BN 128
#define BK 64
#define LDT 72   // padded LDS row stride for legacy (reg-staged) kernels

// async global->LDS, 16B per lane. LDS dest is wave-uniform base + lane*16.
__device__ __forceinline__ void gload_lds16(const void* g, void* l) {
    __builtin_amdgcn_global_load_lds(
        (__attribute__((address_space(1))) void*)g,
        (__attribute__((address_space(3))) void*)l,
        16, 0, 0);
}

// split 8 f32 -> hi/lo bf16x8 (x ~= hi + lo, rel err ~2^-17)
__device__ __forceinline__ void split8(const float* p, bf16x8& hi, bf16x8& lo) {
    const float4* q = (const float4*)p;
    float4 a = q[0], b = q[1];
    float v[8] = { a.x, a.y, a.z, a.w, b.x, b.y, b.z, b.w };
#pragma unroll
    for (int i = 0; i < 8; ++i) {
        bf16_t h = (bf16_t)v[i];
        hi[i] = h;
        lo[i] = (bf16_t)(v[i] - (float)h);
    }
}

// ---- split-precision NT GEMM: C = A (MxK f32) * B^T (NxK f32) + bias ----
// 3-term compensated bf16 MFMA: hi*hi + hi*lo + lo*hi (~f32-grade).
template<bool OUT_SPLIT, bool HAS_BIAS>
__global__ __launch_bounds__(256, 2)
void gemm_nt_split(const float* __restrict__ A, const float* __restrict__ B,
                   const float* __restrict__ bias,
                   void* __restrict__ C0, bf16_t* __restrict__ Clo,
                   int M, int N, int K)
{
    __shared__ bf16_t Ah[BM * LDT];
    __shared__ bf16_t Al[BM * LDT];
    __shared__ bf16_t Bh[BN * LDT];
    __shared__ bf16_t Bl[BN * LDT];

    const int t    = threadIdx.x;
    const int m0   = blockIdx.x * BM;
    const int n0   = blockIdx.y * BN;
    const int lane = t & 63;
    const int wm   = ((t >> 6) & 1) * 64;
    const int wn   = (t >> 7) * 64;
    const int lr   = lane & 15;
    const int lg   = lane >> 4;

    floatx4 acc[4][4] = {};

    for (int k0 = 0; k0 < K; k0 += BK) {
#pragma unroll
        for (int i = 0; i < 4; ++i) {
            int idx = t + i * 256;
            int row = idx >> 3;
            int col = (idx & 7) << 3;
            bf16x8 h, l;
            split8(&A[(size_t)(m0 + row) * K + k0 + col], h, l);
            *(bf16x8*)&Ah[row * LDT + col] = h;
            *(bf16x8*)&Al[row * LDT + col] = l;
            split8(&B[(size_t)(n0 + row) * K + k0 + col], h, l);
            *(bf16x8*)&Bh[row * LDT + col] = h;
            *(bf16x8*)&Bl[row * LDT + col] = l;
        }
        __syncthreads();
#pragma unroll
        for (int ks = 0; ks < BK; ks += 32) {
            bf16x8 ah[4], al[4], bh[4], bl[4];
#pragma unroll
            for (int mi = 0; mi < 4; ++mi) {
                ah[mi] = *(const bf16x8*)&Ah[(wm + mi * 16 + lr) * LDT + ks + lg * 8];
                al[mi] = *(const bf16x8*)&Al[(wm + mi * 16 + lr) * LDT + ks + lg * 8];
            }
#pragma unroll
            for (int ni = 0; ni < 4; ++ni) {
                bh[ni] = *(const bf16x8*)&Bh[(wn + ni * 16 + lr) * LDT + ks + lg * 8];
                bl[ni] = *(const bf16x8*)&Bl[(wn + ni * 16 + lr) * LDT + ks + lg * 8];
            }
#pragma unroll
            for (int mi = 0; mi < 4; ++mi)
#pragma unroll
                for (int ni = 0; ni < 4; ++ni) {
                    acc[mi][ni] = __builtin_amdgcn_mfma_f32_16x16x32_bf16(ah[mi], bh[ni], acc[mi][ni], 0, 0, 0);
                    acc[mi][ni] = __builtin_amdgcn_mfma_f32_16x16x32_bf16(ah[mi], bl[ni], acc[mi][ni], 0, 0, 0);
                    acc[mi][ni] = __builtin_amdgcn_mfma_f32_16x16x32_bf16(al[mi], bh[ni], acc[mi][ni], 0, 0, 0);
                }
        }
        __syncthreads();
    }

#pragma unroll
    for (int mi = 0; mi < 4; ++mi)
#pragma unroll
        for (int ni = 0; ni < 4; ++ni) {
            int col = n0 + wn + ni * 16 + lr;
            float bv = 0.0f;
            if constexpr (HAS_BIAS) bv = bias[col];
#pragma unroll
            for (int r = 0; r < 4; ++r) {
                int row = m0 + wm + mi * 16 + lg * 4 + r;
                float v = acc[mi][ni][r] + bv;
                if constexpr (OUT_SPLIT) {
                    bf16_t h = (bf16_t)v;
                    ((bf16_t*)C0)[(size_t)row * N + col] = h;
                    Clo[(size_t)row * N + col] = (bf16_t)(v - (float)h);
                } else {
                    ((float*)C0)[(size_t)row * N + col] = v;
                }
            }
        }
}

// ---- pre-split NT GEMM via global_load_lds + XOR swizzle ----
// C(f32) = (Ahi+Alo)*(Bhi+Blo)^T; epilogue also emits per-column softmax
// partials (max, sumexp) over this block's 128 rows -> pm/pz[64][8192].
__global__ __launch_bounds__(256, 2)
void gemm_nt_pre_async(const bf16_t* __restrict__ Ahi, const bf16_t* __restrict__ Alo,
                       const bf16_t* __restrict__ Bhi, const bf16_t* __restrict__ Blo,
                       float* __restrict__ C, float* __restrict__ pm,
                       float* __restrict__ pz, int M, int N, int K)
{
    __shared__ bf16_t Ah[BM * BK];
    __shared__ bf16_t Al[BM * BK];
    __shared__ bf16_t Bh[BN * BK];
    __shared__ bf16_t Bl[BN * BK];
    __shared__ float red_m[2][128];
    __shared__ float red_z[2][128];

    const int t    = threadIdx.x;
    const int m0   = blockIdx.x * BM;
    const int n0   = blockIdx.y * BN;
    const int lane = t & 63;
    const int wv   = t >> 6;
    const int widm = (t >> 6) & 1;
    const int wm   = widm * 64;
    const int wn   = (t >> 7) * 64;
    const int lr   = lane & 15;
    const int lg   = lane >> 4;
    const int lrow = lane >> 3;
    const int lcol = (((lane & 7) ^ lrow) * 8);
    const int swz  = (lr & 7) << 3;

    floatx4 acc[4][4] = {};

    for (int k0 = 0; k0 < K; k0 += BK) {
#pragma unroll
        for (int i = 0; i < 4; ++i) {
            const int seg = wv * 4 + i;
            const int row = seg * 8 + lrow;
            const size_t ga = (size_t)(m0 + row) * K + k0 + lcol;
            const size_t gb = (size_t)(n0 + row) * K + k0 + lcol;
            gload_lds16(&Ahi[ga], &Ah[seg * 512]);
            gload_lds16(&Alo[ga], &Al[seg * 512]);
            gload_lds16(&Bhi[gb], &Bh[seg * 512]);
            gload_lds16(&Blo[gb], &Bl[seg * 512]);
        }
        __syncthreads();
#pragma unroll
        for (int ks = 0; ks < BK; ks += 32) {
            const int cA = (ks + lg * 8) ^ swz;
            bf16x8 ah[4], al[4], bh[4], bl[4];
#pragma unroll
            for (int mi = 0; mi < 4; ++mi) {
                ah[mi] = *(const bf16x8*)&Ah[(wm + mi * 16 + lr) * BK + cA];
                al[mi] = *(const bf16x8*)&Al[(wm + mi * 16 + lr) * BK + cA];
            }
#pragma unroll
            for (int ni = 0; ni < 4; ++ni) {
                bh[ni] = *(const bf16x8*)&Bh[(wn + ni * 16 + lr) * BK + cA];
                bl[ni] = *(const bf16x8*)&Bl[(wn + ni * 16 + lr) * BK + cA];
            }
#pragma unroll
            for (int mi = 0; mi < 4; ++mi)
#pragma unroll
                for (int ni = 0; ni < 4; ++ni) {
                    acc[mi][ni] = __builtin_amdgcn_mfma_f32_16x16x32_bf16(ah[mi], bh[ni], acc[mi][ni], 0, 0, 0);
                    acc[mi][ni] = __builtin_amdgcn_mfma_f32_16x16x32_bf16(ah[mi], bl[ni], acc[mi][ni], 0, 0, 0);
                    acc[mi][ni] = __builtin_amdgcn_mfma_f32_16x16x32_bf16(al[mi], bh[ni], acc[mi][ni], 0, 0, 0);
                }
        }
        __syncthreads();
    }

    // ---- C write ----
#pragma unroll
    for (int mi = 0; mi < 4; ++mi)
#pragma unroll
        for (int ni = 0; ni < 4; ++ni) {
            int col = n0 + wn + ni * 16 + lr;
#pragma unroll
            for (int r = 0; r < 4; ++r) {
                int row = m0 + wm + mi * 16 + lg * 4 + r;
                C[(size_t)row * N + col] = acc[mi][ni][r];
            }
        }

    // ---- per-column softmax partial over this block's 128 rows ----
#pragma unroll
    for (int ni = 0; ni < 4; ++ni) {
        float lm = -INFINITY;
#pragma unroll
        for (int mi = 0; mi < 4; ++mi)
#pragma unroll
            for (int r = 0; r < 4; ++r) lm = fmaxf(lm, acc[mi][ni][r]);
        float lz = 0.0f;
#pragma unroll
        for (int mi = 0; mi < 4; ++mi)
#pragma unroll
            for (int r = 0; r < 4; ++r) lz += __expf(acc[mi][ni][r] - lm);
#pragma unroll
        for (int off = 16; off <= 32; off <<= 1) {
            float om = __shfl_xor(lm, off);
            float oz = __shfl_xor(lz, off);
            float nm = fmaxf(lm, om);
            lz = lz * __expf(lm - nm) + oz * __expf(om - nm);
            lm = nm;
        }
        if (lg == 0) {
            red_m[widm][wn + ni * 16 + lr] = lm;
            red_z[widm][wn + ni * 16 + lr] = lz;
        }
    }
    __syncthreads();
    if (t < 128) {
        float a = red_m[0][t], b = red_m[1][t];
        float za = red_z[0][t], zb = red_z[1][t];
        float mb = fmaxf(a, b);
        float z  = za * __expf(a - mb) + zb * __expf(b - mb);
        pm[(size_t)blockIdx.x * 8192 + n0 + t] = mb;
        pz[(size_t)blockIdx.x * 8192 + n0 + t] = z;
    }
}

// ---- plain bf16 NT GEMM via global_load_lds + XOR swizzle: C(f32) = A * B^T ----
// Register-lean variant: acc(64 AGPR) + a[4](16) + 1 live b-frag; forced to
// <=128 unified regs via launch_bounds(256,4) -> 4 blocks/CU (was 2: 140 regs
// landed in the (128,256] band). Same MFMA chain order -> bitwise identical.
__global__ __launch_bounds__(256, 4)
void gemm_nt_bf16_async(const bf16_t* __restrict__ A, const bf16_t* __restrict__ B,
                        float* __restrict__ C, int M, int N, int K)
{
    __shared__ bf16_t As[BM * BK];
    __shared__ bf16_t Bs[BN * BK];

    const int t    = threadIdx.x;
    const int m0   = blockIdx.x * BM;
    const int n0   = blockIdx.y * BN;
    const int lane = t & 63;
    const int wv   = t >> 6;
    const int wm   = ((t >> 6) & 1) * 64;
    const int wn   = (t >> 7) * 64;
    const int lr   = lane & 15;
    const int lg   = lane >> 4;
    const int lrow = lane >> 3;
    const int lcol = (((lane & 7) ^ lrow) * 8);
    const int swz  = (lr & 7) << 3;

    // hoisted staging bases: row for segment i is (wv*4+i)*8 + lrow
    const bf16_t* aBase = A + (size_t)(m0 + wv * 32 + lrow) * K + lcol;
    const bf16_t* bBase = B + (size_t)(n0 + wv * 32 + lrow) * K + lcol;

    floatx4 acc[4][4] = {};

    for (int k0 = 0; k0 < K; k0 += BK) {
#pragma unroll
        for (int i = 0; i < 4; ++i) {
            const int seg = wv * 4 + i;
            gload_lds16(aBase + (size_t)i * 8 * K + k0, &As[seg * 512]);
            gload_lds16(bBase + (size_t)i * 8 * K + k0, &Bs[seg * 512]);
        }
        __syncthreads();
#pragma unroll
        for (int ks = 0; ks < BK; ks += 32) {
            const int cA = (ks + lg * 8) ^ swz;
            bf16x8 a0 = *(const bf16x8*)&As[(wm + 0 * 16 + lr) * BK + cA];
            bf16x8 a1 = *(const bf16x8*)&As[(wm + 1 * 16 + lr) * BK + cA];
            bf16x8 a2 = *(const bf16x8*)&As[(wm + 2 * 16 + lr) * BK + cA];
            bf16x8 a3 = *(const bf16x8*)&As[(wm + 3 * 16 + lr) * BK + cA];
#pragma unroll
            for (int ni = 0; ni < 4; ++ni) {
                bf16x8 b = *(const bf16x8*)&Bs[(wn + ni * 16 + lr) * BK + cA];
                acc[0][ni] = __builtin_amdgcn_mfma_f32_16x16x32_bf16(a0, b, acc[0][ni], 0, 0, 0);
                acc[1][ni] = __builtin_amdgcn_mfma_f32_16x16x32_bf16(a1, b, acc[1][ni], 0, 0, 0);
                acc[2][ni] = __builtin_amdgcn_mfma_f32_16x16x32_bf16(a2, b, acc[2][ni], 0, 0, 0);
                acc[3][ni] = __builtin_amdgcn_mfma_f32_16x16x32_bf16(a3, b, acc[3][ni], 0, 0, 0);
            }
        }
        __syncthreads();
    }

#pragma unroll
    for (int mi = 0; mi < 4; ++mi)
#pragma unroll
        for (int ni = 0; ni < 4; ++ni) {
            int col = n0 + wn + ni * 16 + lr;
#pragma unroll
            for (int r = 0; r < 4; ++r) {
                int row = m0 + wm + mi * 16 + lg * 4 + r;
                C[(size_t)row * N + col] = acc[mi][ni][r];
            }
        }
}

// ---- 64x64-tile transpose + f32->bf16: src [R,C] f32 -> dst [C,R] bf16 ----
__global__ __launch_bounds__(256)
void transpose_to_bf16(const float* __restrict__ src, bf16_t* __restrict__ dst,
                       int R, int Ccols)
{
    __shared__ float tile[64][65];
    const int r0 = blockIdx.x * 64;
    const int c0 = blockIdx.y * 64;
    const int tr = threadIdx.x >> 4;
    const int tc = (threadIdx.x & 15) * 4;
#pragma unroll
    for (int i = 0; i < 4; ++i) {
        int r = tr + i * 16;
        float4 v = *(const float4*)&src[(size_t)(r0 + r) * Ccols + c0 + tc];
        tile[r][tc + 0] = v.x; tile[r][tc + 1] = v.y;
        tile[r][tc + 2] = v.z; tile[r][tc + 3] = v.w;
    }
    __syncthreads();
#pragma unroll
    for (int i = 0; i < 4; ++i) {
        int c = tr + i * 16;
        bf16x4v o = { (bf16_t)tile[tc + 0][c], (bf16_t)tile[tc + 1][c],
                      (bf16_t)tile[tc + 2][c], (bf16_t)tile[tc + 3][c] };
        *(bf16x4v*)&dst[(size_t)(c0 + c) * R + r0 + tc] = o;
    }
}

// ---- column softmax combine over 64 per-block partials ----
__global__ __launch_bounds__(256)
void col_softmax_combine64(const float* __restrict__ pm, const float* __restrict__ pz,
                           float* __restrict__ mf, float* __restrict__ iz)
{
    int j = blockIdx.x * 256 + threadIdx.x;
    float m = -INFINITY;
#pragma unroll
    for (int c = 0; c < 64; ++c) m = fmaxf(m, pm[(size_t)c * 8192 + j]);
    float z = 0.0f;
#pragma unroll
    for (int c = 0; c < 64; ++c) z += pz[(size_t)c * 8192 + j] * __expf(pm[(size_t)c * 8192 + j] - m);
    mf[j] = m;
    iz[j] = 1.0f / z;
}

// normalize + also emit bf16 copy of attns for the fused GEMM
__global__ __launch_bounds__(256)
void normalize_attn_bf16(float* __restrict__ sc, const float* __restrict__ mf,
                         const float* __restrict__ iz, bf16_t* __restrict__ ab)
{
    size_t base = ((size_t)blockIdx.x * 256 + threadIdx.x) * 4;
    int j = (int)(base & 8191);
    float4 s  = *(float4*)&sc[base];
    float4 m4 = *(const float4*)&mf[j];
    float4 z4 = *(const float4*)&iz[j];
    s.x = __expf(s.x - m4.x) * z4.x;
    s.y = __expf(s.y - m4.y) * z4.y;
    s.z = __expf(s.z - m4.z) * z4.z;
    s.w = __expf(s.w - m4.w) * z4.w;
    *(float4*)&sc[base] = s;
    bf16x4v b = { (bf16_t)s.x, (bf16_t)s.y, (bf16_t)s.z, (bf16_t)s.w };
    *(bf16x4v*)&ab[base] = b;
}

extern "C" void kernel_launch(void* const* d_in, const int* in_sizes, int n_in,
                              void* d_out, int out_size, void* d_ws, size_t ws_size,
                              hipStream_t stream) {
    const float* sent  = (const float*)d_in[0];   // [8192,1024]
    const float* knowl = (const float*)d_in[1];   // [8192,2048]
    const float* Ws    = (const float*)d_in[2];   // [1024,1024]
    const float* bs    = (const float*)d_in[3];   // [1024]
    const float* Wk    = (const float*)d_in[4];   // [1024,2048]
    const float* bk    = (const float*)d_in[5];   // [1024]

    float* attns = (float*)d_out;                               // [8192,8192]
    float* fused = (float*)d_out + (size_t)8192 * 8192;         // [8192,2048]

    const size_t MB = 1024 * 1024;
    char* ws = (char*)d_ws;
    dim3 blk(256);

    // layout: Shi(16)@0 Slo(16)@16 Khi(16)@32 Klo(16)@48 [dead after scores]
    //         Ab(128)@0 overlays them; Vt(32)@128; pm/pz@160/162; mf/iz@164
    bf16_t* Shi = (bf16_t*)(ws + 0 * MB);
    bf16_t* Slo = (bf16_t*)(ws + 16 * MB);
    bf16_t* Khi = (bf16_t*)(ws + 32 * MB);
    bf16_t* Klo = (bf16_t*)(ws + 48 * MB);
    bf16_t* Ab  = (bf16_t*)(ws);
    bf16_t* Vt  = (bf16_t*)(ws + 128 * MB);
    float*  pm  = (float*)(ws + 160 * MB);
    float*  pz  = (float*)(ws + 162 * MB);
    float*  mf  = (float*)(ws + 164 * MB);
    float*  iz  = mf + 8192;

    // 1) projections: S = sent @ Ws^T + bs, K = knowl @ Wk^T + bk (split out)
    gemm_nt_split<true, true><<<dim3(64, 8), blk, 0, stream>>>(
        sent, Ws, bs, Shi, Slo, 8192, 1024, 1024);
    gemm_nt_split<true, true><<<dim3(64, 8), blk, 0, stream>>>(
        knowl, Wk, bk, Khi, Klo, 8192, 1024, 2048);
    // 2) scores = S @ K^T (compensated) + per-block softmax partials
    gemm_nt_pre_async<<<dim3(64, 64), blk, 0, stream>>>(
        Shi, Slo, Khi, Klo, attns, pm, pz, 8192, 8192, 1024);
    // 3) Vt = knowl^T bf16 (overlays dead Khi/Klo)
    transpose_to_bf16<<<dim3(128, 32), blk, 0, stream>>>(knowl, Vt, 8192, 2048);
    // 4) softmax combine + normalize (also emits bf16 attns copy into Ab)
    col_softmax_combine64<<<dim3(32), blk, 0, stream>>>(pm, pz, mf, iz);
    normalize_attn_bf16<<<dim3(65536), blk, 0, stream>>>(attns, mf, iz, Ab);
    // 5) fused = attns @ V == Ab @ Vt^T
    gemm_nt_bf16_async<<<dim3(64, 16), blk, 0, stream>>>(
        Ab, Vt, fused, 8192, 2048, 8192);
}